// Round 22
// baseline (50.130 us; speedup 1.0000x reference)
//
#include <hip/hip_runtime.h>

#define BB 2048
#define EMB 128
#define NF 200
#define W_OUT 126
#define EPS 1e-5f

// ws layout (bytes):
// [0, 32768)        G scratch: NCOPY x 1024 floats (zeroed by memset node)
// [32768, 83968)    fcwQh: swizzled fc weights f16, [50][2][64][4]
// [83968, 135168)   AwF: A-matrix f16 in fragment order [50][64][8]
// Fallback (ws < 135168): G = ws[0:1024) 1 copy, AwF at 4096, no swizzle.
#define NCOPY 8
#define FCWQ_BYTE_OFF 32768
#define FCWQ_HALFS (50 * 2 * 64 * 4)    // 25600
#define AWF_BYTE_OFF 83968
#define WS_NEED (AWF_BYTE_OFF + 50 * 64 * 8 * 2)
#define AWF_FALLBACK_OFF 4096

#define SPBS 4                    // stats: samples per block (wave <-> sample)
#define STATS_BLOCKS (BB / SPBS)  // 512
#define SPBM 2                    // main: samples per block (2 waves each)
#define MAIN_BLOCKS (BB / SPBM)   // 1024

typedef _Float16 half8 __attribute__((ext_vector_type(8)));
typedef _Float16 half4v __attribute__((ext_vector_type(4)));
typedef float f32x4v __attribute__((ext_vector_type(4)));

__device__ __forceinline__ const float* rowptr(const int* __restrict__ xr, int r,
                                               const float* __restrict__ er,
                                               const float* __restrict__ ev) {
  if (r == 0) return ev + (size_t)xr[1] * EMB;
  if (r == 1) return er + (size_t)xr[0] * EMB;
  if (r == 2) return ev + (size_t)xr[3] * EMB;
  const int k = (r - 3) >> 1;
  return ((r - 3) & 1) ? ev + (size_t)xr[5 + 2 * k] * EMB
                       : er + (size_t)xr[4 + 2 * k] * EMB;
}

// -------- stats: G32 = sum_s B_s^T B_s via MFMA + fused fcw swizzle ---------
__global__ __launch_bounds__(256, 2) void stats_mfma(
    const int* __restrict__ xb, const float* __restrict__ er,
    const float* __restrict__ ev, float* __restrict__ gout, int ncop,
    const float* __restrict__ fcw, _Float16* __restrict__ fcwQh, int do_swz) {
  __shared__ _Float16 Bt[SPBS][40][136];   // 42.5 KB
  __shared__ float Gred[SPBS][1024];       // 16 KB
  const int tid = threadIdx.x;
  const int base = blockIdx.x * SPBS;

  // fused fcw swizzle: first 100 blocks each handle 256 elements
  if (do_swz && blockIdx.x < (FCWQ_HALFS + 255) / 256) {
    const int idx = blockIdx.x * 256 + tid;
    if (idx < FCWQ_HALFS) {
      const int mtile = idx >> 9;
      const int rem = idx & 511;
      const int jh = rem >> 8;
      const int rem2 = rem & 255;
      const int l = rem2 >> 2;
      const int j = rem2 & 3;
      const int f = mtile * 4 + (l >> 4);  // always < 200
      const int x = (jh * 4 + j) * 16 + (l & 15);
      fcwQh[idx] = (_Float16)((x < W_OUT) ? fcw[(size_t)f * W_OUT + x] : 0.f);
    }
  }

  for (int job = tid; job < SPBS * 136; job += 256) {
    const int s = job / 136, x = job % 136;
    if (x < W_OUT) {
      const int* xr = xb + (size_t)(base + s) * 10;
#pragma unroll
      for (int r = 0; r < 9; r++) {
        const float* hp = rowptr(xr, r, er, ev);
        Bt[s][3 * r + 0][x] = (_Float16)hp[x];
        Bt[s][3 * r + 1][x] = (_Float16)hp[x + 1];
        Bt[s][3 * r + 2][x] = (_Float16)hp[x + 2];
      }
      Bt[s][27][x] = (_Float16)1.0f;
#pragma unroll
      for (int k = 28; k < 40; k++) Bt[s][k][x] = (_Float16)0.f;
    } else {
#pragma unroll
      for (int k = 0; k < 40; k++) Bt[s][k][x] = (_Float16)0.f;
    }
  }
  __syncthreads();

  const int w = tid >> 6, l = tid & 63;
  const int tl = l & 15, kl = l >> 4;
  f32x4v a00 = {0.f, 0.f, 0.f, 0.f}, a01 = a00, a10 = a00, a11 = a00;
#pragma unroll
  for (int c = 0; c < 4; c++) {
    const int x0 = c * 32 + kl * 8;
    const half8 g0 = *(const half8*)&Bt[w][tl][x0];       // taps 0..15
    const half8 g1 = *(const half8*)&Bt[w][16 + tl][x0];  // taps 16..31
    a00 = __builtin_amdgcn_mfma_f32_16x16x32_f16(g0, g0, a00, 0, 0, 0);
    a01 = __builtin_amdgcn_mfma_f32_16x16x32_f16(g0, g1, a01, 0, 0, 0);
    a10 = __builtin_amdgcn_mfma_f32_16x16x32_f16(g1, g0, a10, 0, 0, 0);
    a11 = __builtin_amdgcn_mfma_f32_16x16x32_f16(g1, g1, a11, 0, 0, 0);
  }
  // D layout: row=(l>>4)*4+reg, col=l&15
#pragma unroll
  for (int r = 0; r < 4; r++) {
    const int rm = kl * 4 + r;
    Gred[w][rm * 32 + tl]             = a00[r];
    Gred[w][rm * 32 + 16 + tl]        = a01[r];
    Gred[w][(16 + rm) * 32 + tl]      = a10[r];
    Gred[w][(16 + rm) * 32 + 16 + tl] = a11[r];
  }
  __syncthreads();
  float* gslice = gout + (blockIdx.x & (ncop - 1)) * 1024;
  for (int idx = tid; idx < 1024; idx += 256) {
    float s = Gred[0][idx] + Gred[1][idx] + Gred[2][idx] + Gred[3][idx];
    atomicAdd(&gslice[idx], s);
  }
}

// ---- finalize (1 block): sum G copies -> BN params -> fragment-order A ----
__global__ __launch_bounds__(256) void finalize_kernel(
    const float* __restrict__ w1, const float* __restrict__ w2,
    const float* __restrict__ g1, const float* __restrict__ be1,
    const float* __restrict__ g2, const float* __restrict__ be2,
    const float* __restrict__ gbuf, _Float16* __restrict__ AwF, int ncop) {
  __shared__ float G[1024];
  const int tid = threadIdx.x;
  for (int e = tid; e < 1024; e += 256) {
    float v = 0.f;
    for (int c = 0; c < ncop; c++) v += gbuf[c * 1024 + e];
    G[e] = v;
  }
  __syncthreads();
  const int f = tid;
  if (f >= NF) return;
  float w1r[9], w2r[15];
#pragma unroll
  for (int j = 0; j < 9; j++)  w1r[j] = w1[f * 9 + j];
#pragma unroll
  for (int j = 0; j < 15; j++) w2r[j] = w2[f * 15 + j];
  const float invN = 1.0f / (float)(BB * W_OUT);
  const int m = f >> 2, q4 = (f & 3) * 4;

  float m1 = 0.f, q1 = 0.f;
#pragma unroll
  for (int i = 0; i < 9; i++) {
    m1 = fmaf(w1r[i], G[i * 32 + 27], m1);
#pragma unroll
    for (int j = 0; j < 9; j++) q1 = fmaf(w1r[i] * w1r[j], G[i * 32 + j], q1);
  }
  m1 *= invN;
  float v1 = q1 * invN - m1 * m1;
  float sc1 = g1[f] * rsqrtf(v1 + EPS);
  float sh1 = be1[f] - m1 * sc1;
  {
    float row[32];
#pragma unroll
    for (int k = 0; k < 32; k++) row[k] = 0.f;
#pragma unroll
    for (int i = 0; i < 9; i++) row[i] = w1r[i] * sc1;
    row[27] = sh1;
#pragma unroll
    for (int g = 0; g < 4; g++) {
      half8 h;
#pragma unroll
      for (int e = 0; e < 8; e++) h[e] = (_Float16)row[g * 8 + e];
      *(half8*)&AwF[(size_t)(m * 64 + g * 16 + q4 + 0) * 8] = h;  // conv slot 0
    }
  }

  float mcm = 0.f, qc = 0.f;
#pragma unroll
  for (int i = 0; i < 9; i++) {
    mcm = fmaf(w2r[i], G[i * 32 + 27], mcm);
#pragma unroll
    for (int j = 0; j < 9; j++) qc = fmaf(w2r[i] * w2r[j], G[i * 32 + j], qc);
  }
#pragma unroll
  for (int kk = 0; kk < 3; kk++) {
    const int a = 3 + 2 * kk, b = 4 + 2 * kk;
    float m2 = mcm, cross = 0.f, qa = 0.f, qb = 0.f, qab = 0.f;
#pragma unroll
    for (int j = 0; j < 3; j++) {
      m2 = fmaf(w2r[9 + j],  G[(3 * a + j) * 32 + 27], m2);
      m2 = fmaf(w2r[12 + j], G[(3 * b + j) * 32 + 27], m2);
    }
#pragma unroll
    for (int i = 0; i < 9; i++) {
      float t = 0.f;
#pragma unroll
      for (int j = 0; j < 3; j++) {
        t = fmaf(w2r[9 + j],  G[i * 32 + 3 * a + j], t);
        t = fmaf(w2r[12 + j], G[i * 32 + 3 * b + j], t);
      }
      cross = fmaf(w2r[i], t, cross);
    }
#pragma unroll
    for (int j = 0; j < 3; j++)
#pragma unroll
      for (int jp = 0; jp < 3; jp++) {
        qa  = fmaf(w2r[9 + j]  * w2r[9 + jp],  G[(3 * a + j) * 32 + 3 * a + jp], qa);
        qb  = fmaf(w2r[12 + j] * w2r[12 + jp], G[(3 * b + j) * 32 + 3 * b + jp], qb);
        qab = fmaf(w2r[9 + j]  * w2r[12 + jp], G[(3 * a + j) * 32 + 3 * b + jp], qab);
      }
    float q2 = qc + 2.f * cross + qa + qb + 2.f * qab;
    float mean2 = m2 * invN;
    float v2 = q2 * invN - mean2 * mean2;
    float sck = g2[f] * rsqrtf(v2 + EPS);
    float shk = be2[f] - mean2 * sck;

    float row[32];
#pragma unroll
    for (int k = 0; k < 32; k++) row[k] = 0.f;
#pragma unroll
    for (int i = 0; i < 9; i++) row[i] = w2r[i] * sck;
#pragma unroll
    for (int j = 0; j < 3; j++) {
      row[3 * a + j] = w2r[9 + j]  * sck;
      row[3 * b + j] = w2r[12 + j] * sck;
    }
    row[27] = shk;
#pragma unroll
    for (int g = 0; g < 4; g++) {
      half8 h;
#pragma unroll
      for (int e = 0; e < 8; e++) h[e] = (_Float16)row[g * 8 + e];
      *(half8*)&AwF[(size_t)(m * 64 + g * 16 + q4 + 1 + kk) * 8] = h;
    }
  }
}

// ---- main: Bm-only LDS; af/fq double-buffered (prefetch mtb+1) -------------
template <bool SWZ>
__global__ __launch_bounds__(256, 4) void main_mfma(
    const int* __restrict__ xb, const float* __restrict__ er,
    const float* __restrict__ ev, const float* __restrict__ fcw,
    const _Float16* __restrict__ fcwQh, const _Float16* __restrict__ AwF,
    const float* __restrict__ fcb, float* __restrict__ out) {
  __shared__ _Float16 Bm[SPBM][128][40];   // 20.5 KB only
  __shared__ float red[4];
  const int tid = threadIdx.x;
  const int base = blockIdx.x * SPBM;

  {  // B build: one (s,x) per thread
    const int s = tid >> 7, x = tid & 127;
    const int* xr = xb + (size_t)(base + s) * 10;
    const int x1 = (x + 1 < 128) ? x + 1 : 127;   // cols >= W_OUT masked by fcv
    const int x2 = (x + 2 < 128) ? x + 2 : 127;
    _Float16* dst = &Bm[s][x][0];
#pragma unroll
    for (int r = 0; r < 9; r++) {
      const float* hp = rowptr(xr, r, er, ev);
      dst[3 * r + 0] = (_Float16)hp[x];
      dst[3 * r + 1] = (_Float16)hp[x1];
      dst[3 * r + 2] = (_Float16)hp[x2];
    }
    dst[27] = (_Float16)1.0f;
#pragma unroll
    for (int k = 28; k < 40; k++) dst[k] = (_Float16)0.f;
  }
  __syncthreads();

  const int w = tid >> 6, l = tid & 63;
  const int sW = w >> 1, mh = w & 1;              // sample, M-half (25 tiles)
  const int xl = l & 15, fl = l >> 4;
  const float fcb0 = fcb[0];

#define LOAD_AF(dst, MTB)                                                     \
  _Pragma("unroll")                                                           \
  for (int i_ = 0; i_ < 5; ++i_) {                                            \
    const int mt_ = mh * 25 + (MTB) * 5 + i_;                                 \
    dst[i_] = *(const half8*)&AwF[(size_t)(mt_ * 64 + l) * 8];                \
  }
#define LOAD_FQ(dst, MTB, JH)                                                 \
  _Pragma("unroll")                                                           \
  for (int i_ = 0; i_ < 5; ++i_) {                                            \
    const int mt_ = mh * 25 + (MTB) * 5 + i_;                                 \
    dst[i_] = *(const half4v*)&fcwQh[((size_t)(mt_ * 2 + (JH)) * 64 + l) * 4];\
  }

  float psum = 0.f;
#pragma unroll 1
  for (int jh = 0; jh < 2; ++jh) {
    half8 bf[4];
#pragma unroll
    for (int j = 0; j < 4; ++j)                   // 4 N-tiles resident
      bf[j] = *(const half8*)&Bm[sW][(jh * 4 + j) * 16 + xl][fl * 8];

    half8 afA[5], afB[5];
    half4v fqA[5], fqB[5];
    LOAD_AF(afA, 0)
    if (SWZ) LOAD_FQ(fqA, 0, jh)

#pragma unroll 1
    for (int mtb = 0; mtb < 5; ++mtb) {
      // prefetch next batch while current computes
      if (mtb < 4) {
        LOAD_AF(afB, mtb + 1)
        if (SWZ) LOAD_FQ(fqB, mtb + 1, jh)
      }
#pragma unroll
      for (int i = 0; i < 5; ++i) {
        const int mtile = mh * 25 + mtb * 5 + i;
        const int fo = mtile * 4 + fl;            // < 200 always
#pragma unroll
        for (int j = 0; j < 4; ++j) {
          f32x4v acc = __builtin_amdgcn_mfma_f32_16x16x32_f16(
              afA[i], bf[j], (f32x4v){0.f, 0.f, 0.f, 0.f}, 0, 0, 0);
          float fcv;
          if (SWZ) {
            fcv = (float)fqA[i][j];
          } else {
            const int x = (jh * 4 + j) * 16 + xl;
            const bool xv = (x < W_OUT);
            const float fcl = fcw[(size_t)fo * W_OUT + (xv ? x : 0)];
            fcv = xv ? fcl : 0.f;
          }
          float mv = fminf(fminf(fminf(acc[0], acc[1]), acc[2]), acc[3]);
          psum = fmaf(fmaxf(mv, 0.f), fcv, psum); // min(relu)=relu(min)
        }
      }
      // rotate buffers (static, fully unrolled)
#pragma unroll
      for (int i = 0; i < 5; ++i) { afA[i] = afB[i]; if (SWZ) fqA[i] = fqB[i]; }
    }
  }
#undef LOAD_AF
#undef LOAD_FQ

#pragma unroll
  for (int off = 32; off; off >>= 1) psum += __shfl_xor(psum, off, 64);
  if (l == 0) red[w] = psum;
  __syncthreads();
  if (tid < SPBM)
    out[base + tid] = red[2 * tid] + red[2 * tid + 1] + fcb0;
}

extern "C" void kernel_launch(void* const* d_in, const int* in_sizes, int n_in,
                              void* d_out, int out_size, void* d_ws, size_t ws_size,
                              hipStream_t stream) {
  const int* xb    = (const int*)d_in[0];
  const float* er  = (const float*)d_in[3];
  const float* ev  = (const float*)d_in[4];
  const float* w1  = (const float*)d_in[5];
  const float* g1  = (const float*)d_in[7];
  const float* be1 = (const float*)d_in[8];
  const float* w2  = (const float*)d_in[9];
  const float* g2  = (const float*)d_in[11];
  const float* be2 = (const float*)d_in[12];
  const float* fcw = (const float*)d_in[13];
  const float* fcb = (const float*)d_in[14];
  float* ws  = (float*)d_ws;
  float* out = (float*)d_out;

  const int full = (ws_size >= (size_t)WS_NEED) ? 1 : 0;
  float* gbuf = ws;
  _Float16* fcwQh = (_Float16*)((char*)d_ws + FCWQ_BYTE_OFF);
  _Float16* AwF = (_Float16*)((char*)d_ws +
                              (full ? AWF_BYTE_OFF : AWF_FALLBACK_OFF));
  const int ncop = full ? NCOPY : 1;

  hipMemsetAsync(gbuf, 0, (size_t)ncop * 1024 * sizeof(float), stream);
  hipLaunchKernelGGL(stats_mfma, dim3(STATS_BLOCKS), dim3(256), 0, stream,
                     xb, er, ev, gbuf, ncop, fcw, fcwQh, full);
  hipLaunchKernelGGL(finalize_kernel, dim3(1), dim3(256), 0, stream,
                     w1, w2, g1, be1, g2, be2, gbuf, AwF, ncop);
  if (full)
    hipLaunchKernelGGL((main_mfma<true>), dim3(MAIN_BLOCKS), dim3(256), 0,
                       stream, xb, er, ev, fcw, fcwQh, AwF, fcb, out);
  else
    hipLaunchKernelGGL((main_mfma<false>), dim3(MAIN_BLOCKS), dim3(256), 0,
                       stream, xb, er, ev, fcw, fcwQh, AwF, fcb, out);
}

// Round 23
// 48.666 us; speedup vs baseline: 1.0301x; 1.0301x over previous
//
#include <hip/hip_runtime.h>

#define BB 2048
#define EMB 128
#define NF 200
#define W_OUT 126
#define EPS 1e-5f

// ws layout (bytes):
// [0, 32768)        G scratch: NCOPY x 1024 floats (zeroed by memset node)
// [32768, 83968)    fcwQh: swizzled fc weights f16, [50][2][64][4]
// [83968, 135168)   AwF: A-matrix f16 in fragment order [50][64][8]
// Fallback (ws < 135168): G = ws[0:1024) 1 copy, AwF at 4096, no swizzle.
#define NCOPY 8
#define FCWQ_BYTE_OFF 32768
#define FCWQ_HALFS (50 * 2 * 64 * 4)    // 25600
#define AWF_BYTE_OFF 83968
#define WS_NEED (AWF_BYTE_OFF + 50 * 64 * 8 * 2)
#define AWF_FALLBACK_OFF 4096

#define SPBS 4                    // stats: samples per block (wave <-> sample)
#define STATS_BLOCKS (BB / SPBS)  // 512
#define SPBM 2                    // main: samples per block (2 waves each)
#define MAIN_BLOCKS (BB / SPBM)   // 1024

typedef _Float16 half8 __attribute__((ext_vector_type(8)));
typedef _Float16 half4v __attribute__((ext_vector_type(4)));
typedef float f32x4v __attribute__((ext_vector_type(4)));

__device__ __forceinline__ const float* rowptr(const int* __restrict__ xr, int r,
                                               const float* __restrict__ er,
                                               const float* __restrict__ ev) {
  if (r == 0) return ev + (size_t)xr[1] * EMB;
  if (r == 1) return er + (size_t)xr[0] * EMB;
  if (r == 2) return ev + (size_t)xr[3] * EMB;
  const int k = (r - 3) >> 1;
  return ((r - 3) & 1) ? ev + (size_t)xr[5 + 2 * k] * EMB
                       : er + (size_t)xr[4 + 2 * k] * EMB;
}

// -------- stats: G32 = sum_s B_s^T B_s via MFMA + fused fcw swizzle ---------
__global__ __launch_bounds__(256, 2) void stats_mfma(
    const int* __restrict__ xb, const float* __restrict__ er,
    const float* __restrict__ ev, float* __restrict__ gout, int ncop,
    const float* __restrict__ fcw, _Float16* __restrict__ fcwQh, int do_swz) {
  __shared__ _Float16 Bt[SPBS][40][136];   // 42.5 KB
  __shared__ float Gred[SPBS][1024];       // 16 KB
  const int tid = threadIdx.x;
  const int base = blockIdx.x * SPBS;

  // fused fcw swizzle: first 100 blocks each handle 256 elements
  if (do_swz && blockIdx.x < (FCWQ_HALFS + 255) / 256) {
    const int idx = blockIdx.x * 256 + tid;
    if (idx < FCWQ_HALFS) {
      const int mtile = idx >> 9;
      const int rem = idx & 511;
      const int jh = rem >> 8;
      const int rem2 = rem & 255;
      const int l = rem2 >> 2;
      const int j = rem2 & 3;
      const int f = mtile * 4 + (l >> 4);  // always < 200
      const int x = (jh * 4 + j) * 16 + (l & 15);
      fcwQh[idx] = (_Float16)((x < W_OUT) ? fcw[(size_t)f * W_OUT + x] : 0.f);
    }
  }

  for (int job = tid; job < SPBS * 136; job += 256) {
    const int s = job / 136, x = job % 136;
    if (x < W_OUT) {
      const int* xr = xb + (size_t)(base + s) * 10;
#pragma unroll
      for (int r = 0; r < 9; r++) {
        const float* hp = rowptr(xr, r, er, ev);
        Bt[s][3 * r + 0][x] = (_Float16)hp[x];
        Bt[s][3 * r + 1][x] = (_Float16)hp[x + 1];
        Bt[s][3 * r + 2][x] = (_Float16)hp[x + 2];
      }
      Bt[s][27][x] = (_Float16)1.0f;
#pragma unroll
      for (int k = 28; k < 40; k++) Bt[s][k][x] = (_Float16)0.f;
    } else {
#pragma unroll
      for (int k = 0; k < 40; k++) Bt[s][k][x] = (_Float16)0.f;
    }
  }
  __syncthreads();

  const int w = tid >> 6, l = tid & 63;
  const int tl = l & 15, kl = l >> 4;
  f32x4v a00 = {0.f, 0.f, 0.f, 0.f}, a01 = a00, a10 = a00, a11 = a00;
#pragma unroll
  for (int c = 0; c < 4; c++) {
    const int x0 = c * 32 + kl * 8;
    const half8 g0 = *(const half8*)&Bt[w][tl][x0];       // taps 0..15
    const half8 g1 = *(const half8*)&Bt[w][16 + tl][x0];  // taps 16..31
    a00 = __builtin_amdgcn_mfma_f32_16x16x32_f16(g0, g0, a00, 0, 0, 0);
    a01 = __builtin_amdgcn_mfma_f32_16x16x32_f16(g0, g1, a01, 0, 0, 0);
    a10 = __builtin_amdgcn_mfma_f32_16x16x32_f16(g1, g0, a10, 0, 0, 0);
    a11 = __builtin_amdgcn_mfma_f32_16x16x32_f16(g1, g1, a11, 0, 0, 0);
  }
  // D layout: row=(l>>4)*4+reg, col=l&15
#pragma unroll
  for (int r = 0; r < 4; r++) {
    const int rm = kl * 4 + r;
    Gred[w][rm * 32 + tl]             = a00[r];
    Gred[w][rm * 32 + 16 + tl]        = a01[r];
    Gred[w][(16 + rm) * 32 + tl]      = a10[r];
    Gred[w][(16 + rm) * 32 + 16 + tl] = a11[r];
  }
  __syncthreads();
  float* gslice = gout + (blockIdx.x & (ncop - 1)) * 1024;
  for (int idx = tid; idx < 1024; idx += 256) {
    float s = Gred[0][idx] + Gred[1][idx] + Gred[2][idx] + Gred[3][idx];
    atomicAdd(&gslice[idx], s);
  }
}

// ---- finalize (1 block): sum G copies -> BN params -> fragment-order A ----
__global__ __launch_bounds__(256) void finalize_kernel(
    const float* __restrict__ w1, const float* __restrict__ w2,
    const float* __restrict__ g1, const float* __restrict__ be1,
    const float* __restrict__ g2, const float* __restrict__ be2,
    const float* __restrict__ gbuf, _Float16* __restrict__ AwF, int ncop) {
  __shared__ float G[1024];
  const int tid = threadIdx.x;
  for (int e = tid; e < 1024; e += 256) {
    float v = 0.f;
    for (int c = 0; c < ncop; c++) v += gbuf[c * 1024 + e];
    G[e] = v;
  }
  __syncthreads();
  const int f = tid;
  if (f >= NF) return;
  float w1r[9], w2r[15];
#pragma unroll
  for (int j = 0; j < 9; j++)  w1r[j] = w1[f * 9 + j];
#pragma unroll
  for (int j = 0; j < 15; j++) w2r[j] = w2[f * 15 + j];
  const float invN = 1.0f / (float)(BB * W_OUT);
  const int m = f >> 2, q4 = (f & 3) * 4;

  float m1 = 0.f, q1 = 0.f;
#pragma unroll
  for (int i = 0; i < 9; i++) {
    m1 = fmaf(w1r[i], G[i * 32 + 27], m1);
#pragma unroll
    for (int j = 0; j < 9; j++) q1 = fmaf(w1r[i] * w1r[j], G[i * 32 + j], q1);
  }
  m1 *= invN;
  float v1 = q1 * invN - m1 * m1;
  float sc1 = g1[f] * rsqrtf(v1 + EPS);
  float sh1 = be1[f] - m1 * sc1;
  {
    float row[32];
#pragma unroll
    for (int k = 0; k < 32; k++) row[k] = 0.f;
#pragma unroll
    for (int i = 0; i < 9; i++) row[i] = w1r[i] * sc1;
    row[27] = sh1;
#pragma unroll
    for (int g = 0; g < 4; g++) {
      half8 h;
#pragma unroll
      for (int e = 0; e < 8; e++) h[e] = (_Float16)row[g * 8 + e];
      *(half8*)&AwF[(size_t)(m * 64 + g * 16 + q4 + 0) * 8] = h;  // conv slot 0
    }
  }

  float mcm = 0.f, qc = 0.f;
#pragma unroll
  for (int i = 0; i < 9; i++) {
    mcm = fmaf(w2r[i], G[i * 32 + 27], mcm);
#pragma unroll
    for (int j = 0; j < 9; j++) qc = fmaf(w2r[i] * w2r[j], G[i * 32 + j], qc);
  }
#pragma unroll
  for (int kk = 0; kk < 3; kk++) {
    const int a = 3 + 2 * kk, b = 4 + 2 * kk;
    float m2 = mcm, cross = 0.f, qa = 0.f, qb = 0.f, qab = 0.f;
#pragma unroll
    for (int j = 0; j < 3; j++) {
      m2 = fmaf(w2r[9 + j],  G[(3 * a + j) * 32 + 27], m2);
      m2 = fmaf(w2r[12 + j], G[(3 * b + j) * 32 + 27], m2);
    }
#pragma unroll
    for (int i = 0; i < 9; i++) {
      float t = 0.f;
#pragma unroll
      for (int j = 0; j < 3; j++) {
        t = fmaf(w2r[9 + j],  G[i * 32 + 3 * a + j], t);
        t = fmaf(w2r[12 + j], G[i * 32 + 3 * b + j], t);
      }
      cross = fmaf(w2r[i], t, cross);
    }
#pragma unroll
    for (int j = 0; j < 3; j++)
#pragma unroll
      for (int jp = 0; jp < 3; jp++) {
        qa  = fmaf(w2r[9 + j]  * w2r[9 + jp],  G[(3 * a + j) * 32 + 3 * a + jp], qa);
        qb  = fmaf(w2r[12 + j] * w2r[12 + jp], G[(3 * b + j) * 32 + 3 * b + jp], qb);
        qab = fmaf(w2r[9 + j]  * w2r[12 + jp], G[(3 * a + j) * 32 + 3 * b + jp], qab);
      }
    float q2 = qc + 2.f * cross + qa + qb + 2.f * qab;
    float mean2 = m2 * invN;
    float v2 = q2 * invN - mean2 * mean2;
    float sck = g2[f] * rsqrtf(v2 + EPS);
    float shk = be2[f] - mean2 * sck;

    float row[32];
#pragma unroll
    for (int k = 0; k < 32; k++) row[k] = 0.f;
#pragma unroll
    for (int i = 0; i < 9; i++) row[i] = w2r[i] * sck;
#pragma unroll
    for (int j = 0; j < 3; j++) {
      row[3 * a + j] = w2r[9 + j]  * sck;
      row[3 * b + j] = w2r[12 + j] * sck;
    }
    row[27] = shk;
#pragma unroll
    for (int g = 0; g < 4; g++) {
      half8 h;
#pragma unroll
      for (int e = 0; e < 8; e++) h[e] = (_Float16)row[g * 8 + e];
      *(half8*)&AwF[(size_t)(m * 64 + g * 16 + q4 + 1 + kk) * 8] = h;
    }
  }
}

// ---- main: bf[8] resident; af loaded ONCE per mtile batch (mtb outer) ------
template <bool SWZ>
__global__ __launch_bounds__(256, 4) void main_mfma(
    const int* __restrict__ xb, const float* __restrict__ er,
    const float* __restrict__ ev, const float* __restrict__ fcw,
    const _Float16* __restrict__ fcwQh, const _Float16* __restrict__ AwF,
    const float* __restrict__ fcb, float* __restrict__ out) {
  __shared__ _Float16 Bm[SPBM][128][40];   // 20.5 KB only
  __shared__ float red[4];
  const int tid = threadIdx.x;
  const int base = blockIdx.x * SPBM;

  {  // B build: one (s,x) per thread
    const int s = tid >> 7, x = tid & 127;
    const int* xr = xb + (size_t)(base + s) * 10;
    const int x1 = (x + 1 < 128) ? x + 1 : 127;   // cols >= W_OUT masked by fcv
    const int x2 = (x + 2 < 128) ? x + 2 : 127;
    _Float16* dst = &Bm[s][x][0];
#pragma unroll
    for (int r = 0; r < 9; r++) {
      const float* hp = rowptr(xr, r, er, ev);
      dst[3 * r + 0] = (_Float16)hp[x];
      dst[3 * r + 1] = (_Float16)hp[x1];
      dst[3 * r + 2] = (_Float16)hp[x2];
    }
    dst[27] = (_Float16)1.0f;
#pragma unroll
    for (int k = 28; k < 40; k++) dst[k] = (_Float16)0.f;
  }
  __syncthreads();

  const int w = tid >> 6, l = tid & 63;
  const int sW = w >> 1, mh = w & 1;              // sample, M-half (25 tiles)
  const int xl = l & 15, fl = l >> 4;
  const float fcb0 = fcb[0];

  half8 bf[8];                                    // all 8 N-tiles resident
#pragma unroll
  for (int j = 0; j < 8; ++j)
    bf[j] = *(const half8*)&Bm[sW][j * 16 + xl][fl * 8];

  float psum = 0.f;
#pragma unroll 1
  for (int mtb = 0; mtb < 5; ++mtb) {
    half8 af[5];
#pragma unroll
    for (int i = 0; i < 5; ++i) {                 // 1KB coalesced wave-loads
      const int mtile = mh * 25 + mtb * 5 + i;
      af[i] = *(const half8*)&AwF[(size_t)(mtile * 64 + l) * 8];
    }
#pragma unroll
    for (int i = 0; i < 5; ++i) {                 // each af feeds 8 MFMAs
      const int mtile = mh * 25 + mtb * 5 + i;
      const int fo = mtile * 4 + fl;              // < 200 always
#pragma unroll
      for (int jh = 0; jh < 2; ++jh) {
        half4v fqh;
        if (SWZ)
          fqh = *(const half4v*)&fcwQh[((size_t)(mtile * 2 + jh) * 64 + l) * 4];
#pragma unroll
        for (int j = 0; j < 4; ++j) {
          f32x4v acc = __builtin_amdgcn_mfma_f32_16x16x32_f16(
              af[i], bf[jh * 4 + j], (f32x4v){0.f, 0.f, 0.f, 0.f}, 0, 0, 0);
          float fcv;
          if (SWZ) {
            fcv = (float)fqh[j];
          } else {
            const int x = (jh * 4 + j) * 16 + xl;
            const bool xv = (x < W_OUT);
            const float fcl = fcw[(size_t)fo * W_OUT + (xv ? x : 0)];
            fcv = xv ? fcl : 0.f;
          }
          float mv = fminf(fminf(fminf(acc[0], acc[1]), acc[2]), acc[3]);
          psum = fmaf(fmaxf(mv, 0.f), fcv, psum); // min(relu)=relu(min)
        }
      }
    }
  }

#pragma unroll
  for (int off = 32; off; off >>= 1) psum += __shfl_xor(psum, off, 64);
  if (l == 0) red[w] = psum;
  __syncthreads();
  if (tid < SPBM)
    out[base + tid] = red[2 * tid] + red[2 * tid + 1] + fcb0;
}

extern "C" void kernel_launch(void* const* d_in, const int* in_sizes, int n_in,
                              void* d_out, int out_size, void* d_ws, size_t ws_size,
                              hipStream_t stream) {
  const int* xb    = (const int*)d_in[0];
  const float* er  = (const float*)d_in[3];
  const float* ev  = (const float*)d_in[4];
  const float* w1  = (const float*)d_in[5];
  const float* g1  = (const float*)d_in[7];
  const float* be1 = (const float*)d_in[8];
  const float* w2  = (const float*)d_in[9];
  const float* g2  = (const float*)d_in[11];
  const float* be2 = (const float*)d_in[12];
  const float* fcw = (const float*)d_in[13];
  const float* fcb = (const float*)d_in[14];
  float* ws  = (float*)d_ws;
  float* out = (float*)d_out;

  const int full = (ws_size >= (size_t)WS_NEED) ? 1 : 0;
  float* gbuf = ws;
  _Float16* fcwQh = (_Float16*)((char*)d_ws + FCWQ_BYTE_OFF);
  _Float16* AwF = (_Float16*)((char*)d_ws +
                              (full ? AWF_BYTE_OFF : AWF_FALLBACK_OFF));
  const int ncop = full ? NCOPY : 1;

  hipMemsetAsync(gbuf, 0, (size_t)ncop * 1024 * sizeof(float), stream);
  hipLaunchKernelGGL(stats_mfma, dim3(STATS_BLOCKS), dim3(256), 0, stream,
                     xb, er, ev, gbuf, ncop, fcw, fcwQh, full);
  hipLaunchKernelGGL(finalize_kernel, dim3(1), dim3(256), 0, stream,
                     w1, w2, g1, be1, g2, be2, gbuf, AwF, ncop);
  if (full)
    hipLaunchKernelGGL((main_mfma<true>), dim3(MAIN_BLOCKS), dim3(256), 0,
                       stream, xb, er, ev, fcw, fcwQh, AwF, fcb, out);
  else
    hipLaunchKernelGGL((main_mfma<false>), dim3(MAIN_BLOCKS), dim3(256), 0,
                       stream, xb, er, ev, fcw, fcwQh, AwF, fcb, out);
}

// Round 24
// 46.121 us; speedup vs baseline: 1.0869x; 1.0552x over previous
//
#include <hip/hip_runtime.h>

#define BB 2048
#define EMB 128
#define NF 200
#define W_OUT 126
#define EPS 1e-5f

// ws layout (bytes):
// [0, 32768)        G scratch: NCOPY x 1024 floats (zeroed by memset node)
// [32768, 83968)    fcwQh: swizzled fc weights f16, [50][2][64][4]
// [83968, 135168)   AwF: A-matrix f16 in fragment order [50][64][8]
// Fallback (ws < 135168): G = ws[0:1024) 1 copy, AwF at 4096, no swizzle.
#define NCOPY 8
#define FCWQ_BYTE_OFF 32768
#define FCWQ_HALFS (50 * 2 * 64 * 4)    // 25600
#define AWF_BYTE_OFF 83968
#define WS_NEED (AWF_BYTE_OFF + 50 * 64 * 8 * 2)
#define AWF_FALLBACK_OFF 4096

#define SPBS 4                    // stats: samples per block (wave <-> sample)
#define STATS_BLOCKS (BB / SPBS)  // 512
#define SPBM 2                    // main: samples per block (2 waves each)
#define MAIN_BLOCKS (BB / SPBM)   // 1024
#define FIN_BLOCKS 8              // finalize: 25 f-channels per block

typedef _Float16 half8 __attribute__((ext_vector_type(8)));
typedef _Float16 half4v __attribute__((ext_vector_type(4)));
typedef float f32x4v __attribute__((ext_vector_type(4)));

__device__ __forceinline__ const float* rowptr(const int* __restrict__ xr, int r,
                                               const float* __restrict__ er,
                                               const float* __restrict__ ev) {
  if (r == 0) return ev + (size_t)xr[1] * EMB;
  if (r == 1) return er + (size_t)xr[0] * EMB;
  if (r == 2) return ev + (size_t)xr[3] * EMB;
  const int k = (r - 3) >> 1;
  return ((r - 3) & 1) ? ev + (size_t)xr[5 + 2 * k] * EMB
                       : er + (size_t)xr[4 + 2 * k] * EMB;
}

// -------- stats: G32 = sum_s B_s^T B_s via MFMA + fused fcw swizzle ---------
__global__ __launch_bounds__(256, 2) void stats_mfma(
    const int* __restrict__ xb, const float* __restrict__ er,
    const float* __restrict__ ev, float* __restrict__ gout, int ncop,
    const float* __restrict__ fcw, _Float16* __restrict__ fcwQh, int do_swz) {
  __shared__ _Float16 Bt[SPBS][40][136];   // 42.5 KB
  __shared__ float Gred[SPBS][1024];       // 16 KB
  const int tid = threadIdx.x;
  const int base = blockIdx.x * SPBS;

  // fused fcw swizzle: first 100 blocks each handle 256 elements
  if (do_swz && blockIdx.x < (FCWQ_HALFS + 255) / 256) {
    const int idx = blockIdx.x * 256 + tid;
    if (idx < FCWQ_HALFS) {
      const int mtile = idx >> 9;
      const int rem = idx & 511;
      const int jh = rem >> 8;
      const int rem2 = rem & 255;
      const int l = rem2 >> 2;
      const int j = rem2 & 3;
      const int f = mtile * 4 + (l >> 4);  // always < 200
      const int x = (jh * 4 + j) * 16 + (l & 15);
      fcwQh[idx] = (_Float16)((x < W_OUT) ? fcw[(size_t)f * W_OUT + x] : 0.f);
    }
  }

  for (int job = tid; job < SPBS * 136; job += 256) {
    const int s = job / 136, x = job % 136;
    if (x < W_OUT) {
      const int* xr = xb + (size_t)(base + s) * 10;
#pragma unroll
      for (int r = 0; r < 9; r++) {
        const float* hp = rowptr(xr, r, er, ev);
        Bt[s][3 * r + 0][x] = (_Float16)hp[x];
        Bt[s][3 * r + 1][x] = (_Float16)hp[x + 1];
        Bt[s][3 * r + 2][x] = (_Float16)hp[x + 2];
      }
      Bt[s][27][x] = (_Float16)1.0f;
#pragma unroll
      for (int k = 28; k < 40; k++) Bt[s][k][x] = (_Float16)0.f;
    } else {
#pragma unroll
      for (int k = 0; k < 40; k++) Bt[s][k][x] = (_Float16)0.f;
    }
  }
  __syncthreads();

  const int w = tid >> 6, l = tid & 63;
  const int tl = l & 15, kl = l >> 4;
  f32x4v a00 = {0.f, 0.f, 0.f, 0.f}, a01 = a00, a10 = a00, a11 = a00;
#pragma unroll
  for (int c = 0; c < 4; c++) {
    const int x0 = c * 32 + kl * 8;
    const half8 g0 = *(const half8*)&Bt[w][tl][x0];       // taps 0..15
    const half8 g1 = *(const half8*)&Bt[w][16 + tl][x0];  // taps 16..31
    a00 = __builtin_amdgcn_mfma_f32_16x16x32_f16(g0, g0, a00, 0, 0, 0);
    a01 = __builtin_amdgcn_mfma_f32_16x16x32_f16(g0, g1, a01, 0, 0, 0);
    a10 = __builtin_amdgcn_mfma_f32_16x16x32_f16(g1, g0, a10, 0, 0, 0);
    a11 = __builtin_amdgcn_mfma_f32_16x16x32_f16(g1, g1, a11, 0, 0, 0);
  }
  // D layout: row=(l>>4)*4+reg, col=l&15
#pragma unroll
  for (int r = 0; r < 4; r++) {
    const int rm = kl * 4 + r;
    Gred[w][rm * 32 + tl]             = a00[r];
    Gred[w][rm * 32 + 16 + tl]        = a01[r];
    Gred[w][(16 + rm) * 32 + tl]      = a10[r];
    Gred[w][(16 + rm) * 32 + 16 + tl] = a11[r];
  }
  __syncthreads();
  float* gslice = gout + (blockIdx.x & (ncop - 1)) * 1024;
  for (int idx = tid; idx < 1024; idx += 256) {
    float s = Gred[0][idx] + Gred[1][idx] + Gred[2][idx] + Gred[3][idx];
    atomicAdd(&gslice[idx], s);
  }
}

// ---- finalize (8 blocks): sum G copies -> BN params -> fragment-order A ----
__global__ __launch_bounds__(256) void finalize_kernel(
    const float* __restrict__ w1, const float* __restrict__ w2,
    const float* __restrict__ g1, const float* __restrict__ be1,
    const float* __restrict__ g2, const float* __restrict__ be2,
    const float* __restrict__ gbuf, _Float16* __restrict__ AwF, int ncop) {
  __shared__ float G[1024];
  const int tid = threadIdx.x;
  for (int e = tid; e < 1024; e += 256) {
    float v = 0.f;
    for (int c = 0; c < ncop; c++) v += gbuf[c * 1024 + e];
    G[e] = v;
  }
  __syncthreads();
  const int f = blockIdx.x * (NF / FIN_BLOCKS) + tid;   // 25 channels/block
  if (tid >= NF / FIN_BLOCKS || f >= NF) return;
  float w1r[9], w2r[15];
#pragma unroll
  for (int j = 0; j < 9; j++)  w1r[j] = w1[f * 9 + j];
#pragma unroll
  for (int j = 0; j < 15; j++) w2r[j] = w2[f * 15 + j];
  const float invN = 1.0f / (float)(BB * W_OUT);
  const int m = f >> 2, q4 = (f & 3) * 4;

  float m1 = 0.f, q1 = 0.f;
#pragma unroll
  for (int i = 0; i < 9; i++) {
    m1 = fmaf(w1r[i], G[i * 32 + 27], m1);
#pragma unroll
    for (int j = 0; j < 9; j++) q1 = fmaf(w1r[i] * w1r[j], G[i * 32 + j], q1);
  }
  m1 *= invN;
  float v1 = q1 * invN - m1 * m1;
  float sc1 = g1[f] * rsqrtf(v1 + EPS);
  float sh1 = be1[f] - m1 * sc1;
  {
    float row[32];
#pragma unroll
    for (int k = 0; k < 32; k++) row[k] = 0.f;
#pragma unroll
    for (int i = 0; i < 9; i++) row[i] = w1r[i] * sc1;
    row[27] = sh1;
#pragma unroll
    for (int g = 0; g < 4; g++) {
      half8 h;
#pragma unroll
      for (int e = 0; e < 8; e++) h[e] = (_Float16)row[g * 8 + e];
      *(half8*)&AwF[(size_t)(m * 64 + g * 16 + q4 + 0) * 8] = h;  // conv slot 0
    }
  }

  float mcm = 0.f, qc = 0.f;
#pragma unroll
  for (int i = 0; i < 9; i++) {
    mcm = fmaf(w2r[i], G[i * 32 + 27], mcm);
#pragma unroll
    for (int j = 0; j < 9; j++) qc = fmaf(w2r[i] * w2r[j], G[i * 32 + j], qc);
  }
#pragma unroll
  for (int kk = 0; kk < 3; kk++) {
    const int a = 3 + 2 * kk, b = 4 + 2 * kk;
    float m2 = mcm, cross = 0.f, qa = 0.f, qb = 0.f, qab = 0.f;
#pragma unroll
    for (int j = 0; j < 3; j++) {
      m2 = fmaf(w2r[9 + j],  G[(3 * a + j) * 32 + 27], m2);
      m2 = fmaf(w2r[12 + j], G[(3 * b + j) * 32 + 27], m2);
    }
#pragma unroll
    for (int i = 0; i < 9; i++) {
      float t = 0.f;
#pragma unroll
      for (int j = 0; j < 3; j++) {
        t = fmaf(w2r[9 + j],  G[i * 32 + 3 * a + j], t);
        t = fmaf(w2r[12 + j], G[i * 32 + 3 * b + j], t);
      }
      cross = fmaf(w2r[i], t, cross);
    }
#pragma unroll
    for (int j = 0; j < 3; j++)
#pragma unroll
      for (int jp = 0; jp < 3; jp++) {
        qa  = fmaf(w2r[9 + j]  * w2r[9 + jp],  G[(3 * a + j) * 32 + 3 * a + jp], qa);
        qb  = fmaf(w2r[12 + j] * w2r[12 + jp], G[(3 * b + j) * 32 + 3 * b + jp], qb);
        qab = fmaf(w2r[9 + j]  * w2r[12 + jp], G[(3 * a + j) * 32 + 3 * b + jp], qab);
      }
    float q2 = qc + 2.f * cross + qa + qb + 2.f * qab;
    float mean2 = m2 * invN;
    float v2 = q2 * invN - mean2 * mean2;
    float sck = g2[f] * rsqrtf(v2 + EPS);
    float shk = be2[f] - mean2 * sck;

    float row[32];
#pragma unroll
    for (int k = 0; k < 32; k++) row[k] = 0.f;
#pragma unroll
    for (int i = 0; i < 9; i++) row[i] = w2r[i] * sck;
#pragma unroll
    for (int j = 0; j < 3; j++) {
      row[3 * a + j] = w2r[9 + j]  * sck;
      row[3 * b + j] = w2r[12 + j] * sck;
    }
    row[27] = shk;
#pragma unroll
    for (int g = 0; g < 4; g++) {
      half8 h;
#pragma unroll
      for (int e = 0; e < 8; e++) h[e] = (_Float16)row[g * 8 + e];
      *(half8*)&AwF[(size_t)(m * 64 + g * 16 + q4 + 1 + kk) * 8] = h;
    }
  }
}

// ---- main: R21-exact — Bm-only LDS (4 blocks/CU); af global coalesced ------
template <bool SWZ>
__global__ __launch_bounds__(256, 4) void main_mfma(
    const int* __restrict__ xb, const float* __restrict__ er,
    const float* __restrict__ ev, const float* __restrict__ fcw,
    const _Float16* __restrict__ fcwQh, const _Float16* __restrict__ AwF,
    const float* __restrict__ fcb, float* __restrict__ out) {
  __shared__ _Float16 Bm[SPBM][128][40];   // 20.5 KB only
  __shared__ float red[4];
  const int tid = threadIdx.x;
  const int base = blockIdx.x * SPBM;

  {  // B build: one (s,x) per thread
    const int s = tid >> 7, x = tid & 127;
    const int* xr = xb + (size_t)(base + s) * 10;
    const int x1 = (x + 1 < 128) ? x + 1 : 127;   // cols >= W_OUT masked by fcv
    const int x2 = (x + 2 < 128) ? x + 2 : 127;
    _Float16* dst = &Bm[s][x][0];
#pragma unroll
    for (int r = 0; r < 9; r++) {
      const float* hp = rowptr(xr, r, er, ev);
      dst[3 * r + 0] = (_Float16)hp[x];
      dst[3 * r + 1] = (_Float16)hp[x1];
      dst[3 * r + 2] = (_Float16)hp[x2];
    }
    dst[27] = (_Float16)1.0f;
#pragma unroll
    for (int k = 28; k < 40; k++) dst[k] = (_Float16)0.f;
  }
  __syncthreads();

  const int w = tid >> 6, l = tid & 63;
  const int sW = w >> 1, mh = w & 1;              // sample, M-half (25 tiles)
  const int xl = l & 15, fl = l >> 4;
  const float fcb0 = fcb[0];

  float psum = 0.f;
#pragma unroll 1
  for (int jh = 0; jh < 2; ++jh) {
    half8 bf[4];
#pragma unroll
    for (int j = 0; j < 4; ++j)                   // 4 N-tiles resident
      bf[j] = *(const half8*)&Bm[sW][(jh * 4 + j) * 16 + xl][fl * 8];
#pragma unroll 1
    for (int mtb = 0; mtb < 5; ++mtb) {
      half8 af[5];
#pragma unroll
      for (int i = 0; i < 5; ++i) {               // global, fragment-ordered:
        const int mtile = mh * 25 + mtb * 5 + i;  // 1KB coalesced wave-load
        af[i] = *(const half8*)&AwF[(size_t)(mtile * 64 + l) * 8];
      }
#pragma unroll
      for (int i = 0; i < 5; ++i) {
        const int mtile = mh * 25 + mtb * 5 + i;
        const int fo = mtile * 4 + fl;            // < 200 always
        half4v fqh;
        if (SWZ)
          fqh = *(const half4v*)&fcwQh[((size_t)(mtile * 2 + jh) * 64 + l) * 4];
#pragma unroll
        for (int j = 0; j < 4; ++j) {
          f32x4v acc = __builtin_amdgcn_mfma_f32_16x16x32_f16(
              af[i], bf[j], (f32x4v){0.f, 0.f, 0.f, 0.f}, 0, 0, 0);
          float fcv;
          if (SWZ) {
            fcv = (float)fqh[j];
          } else {
            const int x = (jh * 4 + j) * 16 + xl;
            const bool xv = (x < W_OUT);
            const float fcl = fcw[(size_t)fo * W_OUT + (xv ? x : 0)];
            fcv = xv ? fcl : 0.f;
          }
          float mv = fminf(fminf(fminf(acc[0], acc[1]), acc[2]), acc[3]);
          psum = fmaf(fmaxf(mv, 0.f), fcv, psum); // min(relu)=relu(min)
        }
      }
    }
  }

#pragma unroll
  for (int off = 32; off; off >>= 1) psum += __shfl_xor(psum, off, 64);
  if (l == 0) red[w] = psum;
  __syncthreads();
  if (tid < SPBM)
    out[base + tid] = red[2 * tid] + red[2 * tid + 1] + fcb0;
}

extern "C" void kernel_launch(void* const* d_in, const int* in_sizes, int n_in,
                              void* d_out, int out_size, void* d_ws, size_t ws_size,
                              hipStream_t stream) {
  const int* xb    = (const int*)d_in[0];
  const float* er  = (const float*)d_in[3];
  const float* ev  = (const float*)d_in[4];
  const float* w1  = (const float*)d_in[5];
  const float* g1  = (const float*)d_in[7];
  const float* be1 = (const float*)d_in[8];
  const float* w2  = (const float*)d_in[9];
  const float* g2  = (const float*)d_in[11];
  const float* be2 = (const float*)d_in[12];
  const float* fcw = (const float*)d_in[13];
  const float* fcb = (const float*)d_in[14];
  float* ws  = (float*)d_ws;
  float* out = (float*)d_out;

  const int full = (ws_size >= (size_t)WS_NEED) ? 1 : 0;
  float* gbuf = ws;
  _Float16* fcwQh = (_Float16*)((char*)d_ws + FCWQ_BYTE_OFF);
  _Float16* AwF = (_Float16*)((char*)d_ws +
                              (full ? AWF_BYTE_OFF : AWF_FALLBACK_OFF));
  const int ncop = full ? NCOPY : 1;

  hipMemsetAsync(gbuf, 0, (size_t)ncop * 1024 * sizeof(float), stream);
  hipLaunchKernelGGL(stats_mfma, dim3(STATS_BLOCKS), dim3(256), 0, stream,
                     xb, er, ev, gbuf, ncop, fcw, fcwQh, full);
  hipLaunchKernelGGL(finalize_kernel, dim3(FIN_BLOCKS), dim3(256), 0, stream,
                     w1, w2, g1, be1, g2, be2, gbuf, AwF, ncop);
  if (full)
    hipLaunchKernelGGL((main_mfma<true>), dim3(MAIN_BLOCKS), dim3(256), 0,
                       stream, xb, er, ev, fcw, fcwQh, AwF, fcb, out);
  else
    hipLaunchKernelGGL((main_mfma<false>), dim3(MAIN_BLOCKS), dim3(256), 0,
                       stream, xb, er, ev, fcw, fcwQh, AwF, fcb, out);
}